// Round 1
// baseline (2718.126 us; speedup 1.0000x reference)
//
#include <hip/hip_runtime.h>
#include <math.h>

#define NB   8192   // number of encodings (B)
#define NENC 256    // encoding dim
#define NC   25     // clusters
#define NS   8192   // samples
#define SEL  26     // K+1 : we need the 26th smallest distance
#define TM   128
#define TN   128
#define BK   64

// ---------------- prep: e2, hard argmax, max confidence ----------------
__global__ __launch_bounds__(256) void prep_kernel(
    const float* __restrict__ enc, const float* __restrict__ cat,
    float* __restrict__ e2, float* __restrict__ maxg, int* __restrict__ hard) {
  int gt = blockIdx.x * 256 + threadIdx.x;
  int w = gt >> 6;           // one wave per row
  int lane = gt & 63;
  if (w >= NB) return;

  float4 v = ((const float4*)(enc + (size_t)w * NENC))[lane];  // 64 lanes * 4 = 256
  float ss = v.x * v.x + v.y * v.y + v.z * v.z + v.w * v.w;
  #pragma unroll
  for (int o = 32; o; o >>= 1) ss += __shfl_down(ss, o, 64);

  float mv = -INFINITY;
  int mi = 0;
  if (lane < NC) { mv = cat[(size_t)w * NC + lane]; mi = lane; }
  #pragma unroll
  for (int o = 32; o; o >>= 1) {
    float ov = __shfl_down(mv, o, 64);
    int   oi = __shfl_down(mi, o, 64);
    if (ov > mv || (ov == mv && oi < mi)) { mv = ov; mi = oi; }  // first-occurrence tie-break
  }
  if (lane == 0) { e2[w] = ss; maxg[w] = mv; hard[w] = mi; }
}

// ---------------- f32 distance GEMM: dist[s_local][b] = sqrt(max(q2-2*dot+e2,0)) ----
__global__ __launch_bounds__(256) void dist_gemm(
    const float* __restrict__ enc, const float* __restrict__ e2,
    const int* __restrict__ idxs, float* __restrict__ dist, int s0) {
  __shared__ float As[TM][BK];   // XOR-swizzled: element (r,k) at col ((k>>2)^((r>>3)&7))*4 + (k&3)
  __shared__ float Bs[TN][BK];

  const int t = threadIdx.x;
  const int bm = blockIdx.x, bn = blockIdx.y;
  const int row0 = s0 + bm * TM;   // global query index base
  const int col0 = bn * TN;        // encoding index base
  const int tx = t & 15, ty = t >> 4;

  float acc[8][8];
  #pragma unroll
  for (int i = 0; i < 8; ++i)
    #pragma unroll
    for (int j = 0; j < 8; ++j) acc[i][j] = 0.f;

  for (int kk = 0; kk < NENC; kk += BK) {
    // stage A (gathered query rows) and B tiles, 8 float4 per thread per tile
    #pragma unroll
    for (int u = 0; u < 8; ++u) {
      int f = t + u * 256;             // 0..2047
      int r = f >> 4;                  // tile row
      int k4 = f & 15;                 // float4 within BK
      int sw = k4 ^ ((r >> 3) & 7);
      int g = idxs[row0 + r];
      *(float4*)&As[r][sw << 2] = *((const float4*)(enc + (size_t)g * NENC + kk) + k4);
    }
    #pragma unroll
    for (int u = 0; u < 8; ++u) {
      int f = t + u * 256;
      int r = f >> 4;
      int k4 = f & 15;
      int sw = k4 ^ ((r >> 3) & 7);
      *(float4*)&Bs[r][sw << 2] = *((const float4*)(enc + (size_t)(col0 + r) * NENC + kk) + k4);
    }
    __syncthreads();

    #pragma unroll
    for (int k4 = 0; k4 < 16; ++k4) {
      float4 a4[8], b4[8];
      #pragma unroll
      for (int i = 0; i < 8; ++i) {
        int r = ty * 8 + i;
        a4[i] = *(const float4*)&As[r][(k4 ^ ((r >> 3) & 7)) << 2];
      }
      #pragma unroll
      for (int j = 0; j < 8; ++j) {
        int r = tx * 8 + j;
        b4[j] = *(const float4*)&Bs[r][(k4 ^ ((r >> 3) & 7)) << 2];
      }
      #pragma unroll
      for (int i = 0; i < 8; ++i)
        #pragma unroll
        for (int j = 0; j < 8; ++j)
          acc[i][j] += a4[i].x * b4[j].x + a4[i].y * b4[j].y +
                       a4[i].z * b4[j].z + a4[i].w * b4[j].w;
    }
    __syncthreads();
  }

  float e2c[8], q2r[8];
  #pragma unroll
  for (int j = 0; j < 8; ++j) e2c[j] = e2[col0 + tx * 8 + j];
  #pragma unroll
  for (int i = 0; i < 8; ++i) q2r[i] = e2[idxs[row0 + ty * 8 + i]];

  #pragma unroll
  for (int i = 0; i < 8; ++i) {
    int sl = bm * TM + ty * 8 + i;   // row within the chunk
    float o[8];
    #pragma unroll
    for (int j = 0; j < 8; ++j) {
      float d2 = (q2r[i] - 2.f * acc[i][j]) + e2c[j];   // same assoc as reference
      o[j] = sqrtf(fmaxf(d2, 0.f));
    }
    float* dst = dist + (size_t)sl * NB + col0 + tx * 8;
    *(float4*)dst       = make_float4(o[0], o[1], o[2], o[3]);
    *((float4*)dst + 1) = make_float4(o[4], o[5], o[6], o[7]);
  }
}

// ---------------- per-row exact 26th-smallest + entropy ----------------
__global__ __launch_bounds__(256) void select_entropy(
    const float* __restrict__ dist, const int* __restrict__ hard,
    const float* __restrict__ maxg, const int* __restrict__ idxs,
    float* __restrict__ out, int s0) {
  __shared__ float row[NB];        // 32 KB
  __shared__ int   hist[256];
  __shared__ float wredf[4];
  __shared__ int   wredi[4];
  __shared__ int   binfo[2];
  __shared__ int   chist[NC];

  const int t = threadIdx.x;
  const int lane = t & 63, wv = t >> 6;
  const int sl = blockIdx.x;
  const int s = s0 + sl;

  // load row + running max
  const float4* dr = (const float4*)(dist + (size_t)sl * NB);
  float lmax = 0.f;
  #pragma unroll
  for (int u = 0; u < 8; ++u) {
    int i = t + u * 256;
    float4 v = dr[i];
    ((float4*)row)[i] = v;
    lmax = fmaxf(fmaxf(lmax, fmaxf(v.x, v.y)), fmaxf(v.z, v.w));
  }
  #pragma unroll
  for (int o = 32; o; o >>= 1) lmax = fmaxf(lmax, __shfl_down(lmax, o, 64));
  if (lane == 0) wredf[wv] = lmax;
  hist[t] = 0;                      // 256 threads == 256 bins
  __syncthreads();
  float smax = fmaxf(fmaxf(wredf[0], wredf[1]), fmaxf(wredf[2], wredf[3]));
  float scale = smax > 0.f ? 256.f / smax : 0.f;

  // histogram (monotone binning: ibin(v) nondecreasing in v)
  for (int u = 0; u < 32; ++u) {
    float v = row[t + u * 256];
    int b = (int)(v * scale);
    b = b > 255 ? 255 : b;
    atomicAdd(&hist[b], 1);
  }
  __syncthreads();
  if (t == 0) {
    int cum = 0, j = 0;
    for (; j < 256; ++j) { cum += hist[j]; if (cum >= SEL) break; }
    if (j > 255) j = 255;
    binfo[0] = j;
    binfo[1] = SEL - (cum - hist[j]);   // 1-based rank within bin j
  }
  __syncthreads();
  const int jbin = binfo[0];
  int rank = binfo[1];

  // exact kth by distinct-min extraction within (and after) bin jbin (<=26 iters)
  float kth = 0.f;
  float last = -1.f;
  bool first = true;
  for (int iter = 0; iter < 32; ++iter) {
    float lmin = INFINITY;
    for (int u = 0; u < 32; ++u) {
      float v = row[t + u * 256];
      bool elig;
      if (first) {
        int b = (int)(v * scale);
        b = b > 255 ? 255 : b;
        elig = (b >= jbin);
      } else {
        elig = (v > last);
      }
      if (elig) lmin = fminf(lmin, v);
    }
    #pragma unroll
    for (int o = 32; o; o >>= 1) lmin = fminf(lmin, __shfl_down(lmin, o, 64));
    __syncthreads();
    if (lane == 0) wredf[wv] = lmin;
    __syncthreads();
    float m = fminf(fminf(wredf[0], wredf[1]), fminf(wredf[2], wredf[3]));

    int lc = 0;
    for (int u = 0; u < 32; ++u) lc += (row[t + u * 256] == m) ? 1 : 0;
    #pragma unroll
    for (int o = 32; o; o >>= 1) lc += __shfl_down(lc, o, 64);
    __syncthreads();
    if (lane == 0) wredi[wv] = lc;
    __syncthreads();
    int c = wredi[0] + wredi[1] + wredi[2] + wredi[3];

    kth = m;
    if (c >= rank) break;
    rank -= c;
    last = m;
    first = false;
  }

  // neighborhood cluster counts (strict <, matching reference mask)
  if (t < NC) chist[t] = 0;
  __syncthreads();
  int ln = 0;
  for (int u = 0; u < 32; ++u) {
    int i = t + u * 256;
    if (row[i] < kth) { atomicAdd(&chist[hard[i]], 1); ++ln; }
  }
  #pragma unroll
  for (int o = 32; o; o >>= 1) ln += __shfl_down(ln, o, 64);
  __syncthreads();               // atomics visible
  if (lane == 0) wredi[wv] = ln;
  __syncthreads();
  if (t == 0) {
    float fn = (float)(wredi[0] + wredi[1] + wredi[2] + wredi[3]);
    float pur = 0.f;
    for (int c = 0; c < NC; ++c) {
      float p = (float)chist[c] / fn;
      pur -= p * logf(p + 1e-5f);
    }
    out[s] = pur * maxg[idxs[s]];
  }
}

// ---------------- launch ----------------
extern "C" void kernel_launch(void* const* d_in, const int* in_sizes, int n_in,
                              void* d_out, int out_size, void* d_ws, size_t ws_size,
                              hipStream_t stream) {
  const float* enc = (const float*)d_in[0];
  const float* cat = (const float*)d_in[1];
  const int* idxs = (const int*)d_in[2];
  float* out = (float*)d_out;

  float* e2   = (float*)d_ws;
  float* maxg = e2 + NB;
  int*   hard = (int*)(maxg + NB);
  float* dist = (float*)(hard + NB);

  size_t head  = (size_t)NB * 12;
  size_t avail = ws_size > head ? ws_size - head : 0;
  long long cmax = (long long)(avail / ((size_t)NB * 4));
  int chunk = (int)(cmax > NS ? NS : cmax);
  chunk &= ~(TM - 1);
  if (chunk > 2048) chunk = 2048;   // keep dist chunk (64MB) L3-resident
  if (chunk < TM) chunk = TM;

  prep_kernel<<<dim3(NB / 4), dim3(256), 0, stream>>>(enc, cat, e2, maxg, hard);

  for (int s0 = 0; s0 < NS; s0 += chunk) {
    int rows = (NS - s0 < chunk) ? (NS - s0) : chunk;
    dist_gemm<<<dim3(rows / TM, NB / TN), dim3(256), 0, stream>>>(enc, e2, idxs, dist, s0);
    select_entropy<<<dim3(rows), dim3(256), 0, stream>>>(dist, hard, maxg, idxs, out, s0);
  }
}

// Round 2
// 232.249 us; speedup vs baseline: 11.7035x; 11.7035x over previous
//
#include <hip/hip_runtime.h>
#include <hip/hip_fp16.h>
#include <hip/hip_bf16.h>
#include <math.h>

#define NB   8192
#define NENC 256
#define NC   25
#define NS   8192
#define SEL  26      // K+1
#define MARGIN 2.0f  // d2-units candidate margin (covers bf16-hi approx + f16 storage error)

typedef __attribute__((ext_vector_type(8))) short short8;
typedef __attribute__((ext_vector_type(4))) float f32x4;

__device__ __forceinline__ void gload_lds16(const void* g, void* l) {
  __builtin_amdgcn_global_load_lds(
      (const __attribute__((address_space(1))) unsigned int*)g,
      (__attribute__((address_space(3))) unsigned int*)l,
      16, 0, 0);
}

// ---------------- prep: e2, hard argmax, max confidence ----------------
__global__ __launch_bounds__(256) void prep_kernel(
    const float* __restrict__ enc, const float* __restrict__ cat,
    float* __restrict__ e2, float* __restrict__ maxg, int* __restrict__ hard) {
  int gt = blockIdx.x * 256 + threadIdx.x;
  int w = gt >> 6;
  int lane = gt & 63;
  if (w >= NB) return;

  float4 v = ((const float4*)(enc + (size_t)w * NENC))[lane];
  float ss = v.x * v.x + v.y * v.y + v.z * v.z + v.w * v.w;
  #pragma unroll
  for (int o = 32; o; o >>= 1) ss += __shfl_down(ss, o, 64);

  float mv = -INFINITY;
  int mi = 0;
  if (lane < NC) { mv = cat[(size_t)w * NC + lane]; mi = lane; }
  #pragma unroll
  for (int o = 32; o; o >>= 1) {
    float ov = __shfl_down(mv, o, 64);
    int   oi = __shfl_down(mi, o, 64);
    if (ov > mv || (ov == mv && oi < mi)) { mv = ov; mi = oi; }
  }
  if (lane == 0) { e2[w] = ss; maxg[w] = mv; hard[w] = mi; }
}

// ---------------- bf16 conversion of encodings (B matrix) ----------------
__global__ __launch_bounds__(256) void convB(const float* __restrict__ enc,
                                             ushort* __restrict__ Bbf) {
  int f = blockIdx.x * 256 + threadIdx.x;   // float4 index, NB*NENC/4 total
  float4 v = ((const float4*)enc)[f];
  ushort4 o;
  __hip_bfloat16 h;
  h = __float2bfloat16(v.x); o.x = *(unsigned short*)&h;
  h = __float2bfloat16(v.y); o.y = *(unsigned short*)&h;
  h = __float2bfloat16(v.z); o.z = *(unsigned short*)&h;
  h = __float2bfloat16(v.w); o.w = *(unsigned short*)&h;
  ((ushort4*)Bbf)[f] = o;
}

// ---------------- gather query rows as bf16 + q2 ----------------
__global__ __launch_bounds__(256) void gatherA(
    const float* __restrict__ enc, const int* __restrict__ idxs,
    const float* __restrict__ e2, ushort* __restrict__ Abf,
    float* __restrict__ q2) {
  int f = blockIdx.x * 256 + threadIdx.x;   // float4 index, NS*NENC/4 total
  int s = f >> 6, c4 = f & 63;
  int qi = idxs[s];
  float4 v = ((const float4*)(enc + (size_t)qi * NENC))[c4];
  ushort4 o;
  __hip_bfloat16 h;
  h = __float2bfloat16(v.x); o.x = *(unsigned short*)&h;
  h = __float2bfloat16(v.y); o.y = *(unsigned short*)&h;
  h = __float2bfloat16(v.z); o.z = *(unsigned short*)&h;
  h = __float2bfloat16(v.w); o.w = *(unsigned short*)&h;
  ((ushort4*)Abf)[f] = o;
  if (c4 == 0) q2[s] = e2[qi];
}

// ---------------- bf16 MFMA GEMM -> approx d2 as f16 ----------------
// 128x128 tile, BK=64, 4 waves (2x2), each wave 64x64 = 4x4 frags of 16x16x32.
__global__ __launch_bounds__(256) void d2gemm(
    const ushort* __restrict__ Abf, const ushort* __restrict__ Bbf,
    const float* __restrict__ q2, const float* __restrict__ e2,
    __half* __restrict__ dist) {
  __shared__ ushort lds[16384];     // As = [0,8192), Bs = [8192,16384); 32 KB

  const int t = threadIdx.x, lane = t & 63, w = t >> 6;
  const int bm = blockIdx.x, bn = blockIdx.y;
  const int wm = w >> 1, wn = w & 1;

  f32x4 acc[4][4];
  #pragma unroll
  for (int i = 0; i < 4; ++i)
    #pragma unroll
    for (int j = 0; j < 4; ++j) acc[i][j] = (f32x4){0.f, 0.f, 0.f, 0.f};

  for (int kk = 0; kk < NENC; kk += 64) {
    if (kk) __syncthreads();
    // stage A and B via global_load_lds (linear LDS dest, pre-swizzled global src)
    #pragma unroll
    for (int u = 0; u < 4; ++u) {
      int flat = (u * 4 + w) * 64 + lane;
      int r = flat >> 3, c = flat & 7;
      const ushort* ga = Abf + ((size_t)(bm * 128 + r)) * NENC + kk + ((c ^ (r & 7)) << 3);
      gload_lds16(ga, (char*)lds + (u * 4 + w) * 1024);
    }
    #pragma unroll
    for (int u = 0; u < 4; ++u) {
      int flat = (u * 4 + w) * 64 + lane;
      int r = flat >> 3, c = flat & 7;
      const ushort* gb = Bbf + ((size_t)(bn * 128 + r)) * NENC + kk + ((c ^ (r & 7)) << 3);
      gload_lds16(gb, (char*)lds + 16384 + (u * 4 + w) * 1024);
    }
    __syncthreads();

    #pragma unroll
    for (int kf = 0; kf < 2; ++kf) {
      short8 af[4], bg[4];
      int ch = kf * 4 + (lane >> 4);
      #pragma unroll
      for (int i = 0; i < 4; ++i) {
        int r = wm * 64 + i * 16 + (lane & 15);
        af[i] = *(const short8*)&lds[r * 64 + ((ch ^ (r & 7)) * 8)];
      }
      #pragma unroll
      for (int j = 0; j < 4; ++j) {
        int r = wn * 64 + j * 16 + (lane & 15);
        bg[j] = *(const short8*)&lds[8192 + r * 64 + ((ch ^ (r & 7)) * 8)];
      }
      #pragma unroll
      for (int i = 0; i < 4; ++i)
        #pragma unroll
        for (int j = 0; j < 4; ++j)
          acc[i][j] = __builtin_amdgcn_mfma_f32_16x16x32_bf16(af[i], bg[j], acc[i][j], 0, 0, 0);
    }
  }
  __syncthreads();

  // epilogue: d2 = (q2 - 2*dot) + e2 -> f16, swizzled LDS, coalesced store
  ushort* lo = lds;   // reuse as 128x128 f16
  float e2v[4];
  #pragma unroll
  for (int j = 0; j < 4; ++j) e2v[j] = e2[bn * 128 + wn * 64 + j * 16 + (lane & 15)];

  #pragma unroll
  for (int i = 0; i < 4; ++i) {
    int rb = wm * 64 + i * 16 + (lane >> 4) * 4;
    float q2v[4];
    #pragma unroll
    for (int reg = 0; reg < 4; ++reg) q2v[reg] = q2[bm * 128 + rb + reg];
    #pragma unroll
    for (int j = 0; j < 4; ++j) {
      int tc = wn * 64 + j * 16 + (lane & 15);
      #pragma unroll
      for (int reg = 0; reg < 4; ++reg) {
        int tr = rb + reg;
        float d2 = (q2v[reg] - 2.0f * acc[i][j][reg]) + e2v[j];
        __half h = __float2half(d2);
        lo[tr * 128 + (tc ^ ((tr & 7) << 4))] = __half_as_ushort(h);
      }
    }
  }
  __syncthreads();

  #pragma unroll
  for (int m = 0; m < 8; ++m) {
    int f = t + m * 256;               // 16B-chunk id, 2048 total
    int row = f >> 4, cc = f & 15;
    short8 v = *(const short8*)&lo[row * 128 + ((cc ^ ((row & 7) << 1)) * 8)];
    *(short8*)((ushort*)dist + ((size_t)(bm * 128 + row)) * NB + bn * 128 + cc * 8) = v;
  }
}

// ---------------- select: approx kth -> candidates -> exact refine -> entropy ----
__global__ __launch_bounds__(256) void select_entropy(
    const __half* __restrict__ dist, const float* __restrict__ enc,
    const float* __restrict__ e2, const int* __restrict__ hard,
    const float* __restrict__ maxg, const int* __restrict__ idxs,
    float* __restrict__ out, int s0) {
  __shared__ ushort rowv[NB];      // 16 KB
  __shared__ float qv[NENC];
  __shared__ float cd[128];
  __shared__ int   cidx[128];
  __shared__ int   hist[256];
  __shared__ int   chist[NC];
  __shared__ float redf[4];
  __shared__ int   ncand, ncnt;
  __shared__ float kthv, thrv;

  const int t = threadIdx.x, lane = t & 63, wv = t >> 6;
  const int s = s0 + blockIdx.x;
  const int qi = idxs[s];

  // load f16 row + row max
  float lmax = 0.f;
  const short8* src = (const short8*)(dist + (size_t)blockIdx.x * NB);
  #pragma unroll
  for (int u = 0; u < 4; ++u) {
    short8 v = src[t + u * 256];
    ((short8*)rowv)[t + u * 256] = v;
    #pragma unroll
    for (int e = 0; e < 8; ++e) {
      float f = __half2float(__ushort_as_half((unsigned short)v[e]));
      lmax = fmaxf(lmax, f);
    }
  }
  hist[t] = 0;
  if (t == 0) { ncand = 0; ncnt = 0; }
  if (t < NC) chist[t] = 0;
  #pragma unroll
  for (int o = 32; o; o >>= 1) lmax = fmaxf(lmax, __shfl_down(lmax, o, 64));
  if (lane == 0) redf[wv] = lmax;
  __syncthreads();
  float rmax = fmaxf(fmaxf(redf[0], redf[1]), fmaxf(redf[2], redf[3]));
  float scale = 255.0f / (rmax + 1e-6f);

  // histogram of approx d2
  for (int u = 0; u < 32; ++u) {
    float v = __half2float(__ushort_as_half(rowv[t + u * 256]));
    int b = (int)(v * scale);
    b = b < 0 ? 0 : (b > 255 ? 255 : b);
    atomicAdd(&hist[b], 1);
  }
  __syncthreads();
  if (t == 0) {
    int cum = 0, j = 0;
    for (; j < 256; ++j) { cum += hist[j]; if (cum >= SEL) break; }
    thrv = (float)(j + 1) / scale + MARGIN;   // upper bin edge + margin
  }
  __syncthreads();
  float thr = thrv;

  // collect candidate indices
  for (int u = 0; u < 32; ++u) {
    int i = t + u * 256;
    float v = __half2float(__ushort_as_half(rowv[i]));
    if (v <= thr) {
      int p = atomicAdd(&ncand, 1);
      if (p < 128) cidx[p] = i;
    }
  }
  qv[t] = enc[(size_t)qi * NENC + t];
  __syncthreads();
  int nc = ncand; if (nc > 128) nc = 128;
  float q2v = e2[qi];

  // exact f32 distance for each candidate (one wave per candidate, strided)
  float4 q4 = ((const float4*)qv)[lane];
  for (int c = wv; c < nc; c += 4) {
    int bidx = cidx[c];
    float4 ev = ((const float4*)(enc + (size_t)bidx * NENC))[lane];
    float p = q4.x * ev.x + q4.y * ev.y + q4.z * ev.z + q4.w * ev.w;
    #pragma unroll
    for (int o = 32; o; o >>= 1) p += __shfl_down(p, o, 64);
    if (lane == 0) {
      float d2 = (q2v - 2.0f * p) + e2[bidx];
      cd[c] = sqrtf(fmaxf(d2, 0.f));
    }
  }
  __syncthreads();

  // exact 26th smallest among candidates (contains all true top-26)
  if (t < nc) {
    float mv = cd[t];
    int less = 0, eq = 0;
    for (int j = 0; j < nc; ++j) { float o = cd[j]; less += (o < mv); eq += (o == mv); }
    if (less <= SEL - 1 && less + eq > SEL - 1) kthv = mv;
  }
  __syncthreads();
  float kv = kthv;

  if (t < nc && cd[t] < kv) {
    atomicAdd(&chist[hard[cidx[t]]], 1);
    atomicAdd(&ncnt, 1);
  }
  __syncthreads();
  if (t == 0) {
    float fn = (float)ncnt;
    float pur = 0.f;
    for (int c = 0; c < NC; ++c) {
      float p = (float)chist[c] / fn;
      pur -= p * logf(p + 1e-5f);
    }
    out[s] = pur * maxg[qi];
  }
}

// ---------------- launch ----------------
extern "C" void kernel_launch(void* const* d_in, const int* in_sizes, int n_in,
                              void* d_out, int out_size, void* d_ws, size_t ws_size,
                              hipStream_t stream) {
  const float* enc = (const float*)d_in[0];
  const float* cat = (const float*)d_in[1];
  const int* idxs = (const int*)d_in[2];
  float* out = (float*)d_out;

  char* ws = (char*)d_ws;
  float* e2   = (float*)ws;
  float* maxg = e2 + NB;
  int*   hard = (int*)(maxg + NB);
  float* q2   = (float*)(hard + NB);
  ushort* Abf = (ushort*)(q2 + NB);
  ushort* Bbf = Abf + (size_t)NS * NENC;
  __half* dist = (__half*)(Bbf + (size_t)NB * NENC);

  size_t head = (size_t)((char*)dist - ws);
  size_t avail = ws_size > head ? ws_size - head : 0;
  long long cmax = (long long)(avail / ((size_t)NB * 2));
  int chunk = (int)(cmax > NS ? NS : cmax);
  chunk &= ~127;
  if (chunk < 128) chunk = 128;

  prep_kernel<<<dim3(NB / 4), dim3(256), 0, stream>>>(enc, cat, e2, maxg, hard);
  convB<<<dim3(NB * NENC / 4 / 256), dim3(256), 0, stream>>>(enc, Bbf);
  gatherA<<<dim3(NS * NENC / 4 / 256), dim3(256), 0, stream>>>(enc, idxs, e2, Abf, q2);

  for (int s0 = 0; s0 < NS; s0 += chunk) {
    int rows = (NS - s0 < chunk) ? (NS - s0) : chunk;
    d2gemm<<<dim3(rows / 128, NB / 128), dim3(256), 0, stream>>>(
        Abf + (size_t)s0 * NENC, Bbf, q2 + s0, e2, dist);
    select_entropy<<<dim3(rows), dim3(256), 0, stream>>>(
        dist, enc, e2, hard, maxg, idxs, out, s0);
  }
}

// Round 3
// 216.251 us; speedup vs baseline: 12.5693x; 1.0740x over previous
//
#include <hip/hip_runtime.h>
#include <hip/hip_fp16.h>
#include <hip/hip_bf16.h>
#include <math.h>

#define NB   8192
#define NENC 256
#define NC   25
#define NS   8192
#define SEL  26      // K+1
#define CMARG 2.0f   // collect margin in d2 units (covers 2x approx eps ~0.5)
#define CAP  1024

typedef __attribute__((ext_vector_type(8))) short short8;
typedef __attribute__((ext_vector_type(4))) float f32x4;

__device__ __forceinline__ void gload_lds16(const void* g, void* l) {
  __builtin_amdgcn_global_load_lds(
      (const __attribute__((address_space(1))) unsigned int*)g,
      (__attribute__((address_space(3))) unsigned int*)l,
      16, 0, 0);
}

__device__ __forceinline__ float h2f(unsigned short u) {
  return __half2float(__ushort_as_half(u));
}

// ---------------- prep: e2, argmax, confidence, bf16 B ----------------
__global__ __launch_bounds__(256) void prep_kernel(
    const float* __restrict__ enc, const float* __restrict__ cat,
    float* __restrict__ e2, float* __restrict__ maxg, int* __restrict__ hard,
    ushort* __restrict__ Bbf) {
  int gt = blockIdx.x * 256 + threadIdx.x;
  int w = gt >> 6;           // one wave per row
  int lane = gt & 63;

  float4 v = ((const float4*)(enc + (size_t)w * NENC))[lane];
  ushort4 o;
  __hip_bfloat16 h;
  h = __float2bfloat16(v.x); o.x = *(unsigned short*)&h;
  h = __float2bfloat16(v.y); o.y = *(unsigned short*)&h;
  h = __float2bfloat16(v.z); o.z = *(unsigned short*)&h;
  h = __float2bfloat16(v.w); o.w = *(unsigned short*)&h;
  ((ushort4*)(Bbf + (size_t)w * NENC))[lane] = o;

  float ss = v.x * v.x + v.y * v.y + v.z * v.z + v.w * v.w;
  #pragma unroll
  for (int ofs = 32; ofs; ofs >>= 1) ss += __shfl_down(ss, ofs, 64);

  float mv = -INFINITY;
  int mi = 0;
  if (lane < NC) { mv = cat[(size_t)w * NC + lane]; mi = lane; }
  #pragma unroll
  for (int ofs = 32; ofs; ofs >>= 1) {
    float ov = __shfl_down(mv, ofs, 64);
    int   oi = __shfl_down(mi, ofs, 64);
    if (ov > mv || (ov == mv && oi < mi)) { mv = ov; mi = oi; }
  }
  if (lane == 0) { e2[w] = ss; maxg[w] = mv; hard[w] = mi; }
}

// ---------------- gather query rows as bf16 + q2 ----------------
__global__ __launch_bounds__(256) void gatherA(
    const float* __restrict__ enc, const int* __restrict__ idxs,
    const float* __restrict__ e2, ushort* __restrict__ Abf,
    float* __restrict__ q2) {
  int f = blockIdx.x * 256 + threadIdx.x;
  int s = f >> 6, c4 = f & 63;
  int qi = idxs[s];
  float4 v = ((const float4*)(enc + (size_t)qi * NENC))[c4];
  ushort4 o;
  __hip_bfloat16 h;
  h = __float2bfloat16(v.x); o.x = *(unsigned short*)&h;
  h = __float2bfloat16(v.y); o.y = *(unsigned short*)&h;
  h = __float2bfloat16(v.z); o.z = *(unsigned short*)&h;
  h = __float2bfloat16(v.w); o.w = *(unsigned short*)&h;
  ((ushort4*)Abf)[f] = o;
  if (c4 == 0) q2[s] = e2[qi];
}

// ---------------- bf16 MFMA GEMM -> approx d2 as f16 (unchanged, verified) ----
__global__ __launch_bounds__(256) void d2gemm(
    const ushort* __restrict__ Abf, const ushort* __restrict__ Bbf,
    const float* __restrict__ q2, const float* __restrict__ e2,
    __half* __restrict__ dist) {
  __shared__ ushort lds[16384];

  const int t = threadIdx.x, lane = t & 63, w = t >> 6;
  const int bm = blockIdx.x, bn = blockIdx.y;
  const int wm = w >> 1, wn = w & 1;

  f32x4 acc[4][4];
  #pragma unroll
  for (int i = 0; i < 4; ++i)
    #pragma unroll
    for (int j = 0; j < 4; ++j) acc[i][j] = (f32x4){0.f, 0.f, 0.f, 0.f};

  for (int kk = 0; kk < NENC; kk += 64) {
    if (kk) __syncthreads();
    #pragma unroll
    for (int u = 0; u < 4; ++u) {
      int flat = (u * 4 + w) * 64 + lane;
      int r = flat >> 3, c = flat & 7;
      const ushort* ga = Abf + ((size_t)(bm * 128 + r)) * NENC + kk + ((c ^ (r & 7)) << 3);
      gload_lds16(ga, (char*)lds + (u * 4 + w) * 1024);
    }
    #pragma unroll
    for (int u = 0; u < 4; ++u) {
      int flat = (u * 4 + w) * 64 + lane;
      int r = flat >> 3, c = flat & 7;
      const ushort* gb = Bbf + ((size_t)(bn * 128 + r)) * NENC + kk + ((c ^ (r & 7)) << 3);
      gload_lds16(gb, (char*)lds + 16384 + (u * 4 + w) * 1024);
    }
    __syncthreads();

    #pragma unroll
    for (int kf = 0; kf < 2; ++kf) {
      short8 af[4], bg[4];
      int ch = kf * 4 + (lane >> 4);
      #pragma unroll
      for (int i = 0; i < 4; ++i) {
        int r = wm * 64 + i * 16 + (lane & 15);
        af[i] = *(const short8*)&lds[r * 64 + ((ch ^ (r & 7)) * 8)];
      }
      #pragma unroll
      for (int j = 0; j < 4; ++j) {
        int r = wn * 64 + j * 16 + (lane & 15);
        bg[j] = *(const short8*)&lds[8192 + r * 64 + ((ch ^ (r & 7)) * 8)];
      }
      #pragma unroll
      for (int i = 0; i < 4; ++i)
        #pragma unroll
        for (int j = 0; j < 4; ++j)
          acc[i][j] = __builtin_amdgcn_mfma_f32_16x16x32_bf16(af[i], bg[j], acc[i][j], 0, 0, 0);
    }
  }
  __syncthreads();

  ushort* lo = lds;
  float e2v[4];
  #pragma unroll
  for (int j = 0; j < 4; ++j) e2v[j] = e2[bn * 128 + wn * 64 + j * 16 + (lane & 15)];

  #pragma unroll
  for (int i = 0; i < 4; ++i) {
    int rb = wm * 64 + i * 16 + (lane >> 4) * 4;
    float q2v[4];
    #pragma unroll
    for (int reg = 0; reg < 4; ++reg) q2v[reg] = q2[bm * 128 + rb + reg];
    #pragma unroll
    for (int j = 0; j < 4; ++j) {
      int tc = wn * 64 + j * 16 + (lane & 15);
      #pragma unroll
      for (int reg = 0; reg < 4; ++reg) {
        int tr = rb + reg;
        float d2 = (q2v[reg] - 2.0f * acc[i][j][reg]) + e2v[j];
        __half hh = __float2half(d2);
        lo[tr * 128 + (tc ^ ((tr & 7) << 4))] = __half_as_ushort(hh);
      }
    }
  }
  __syncthreads();

  #pragma unroll
  for (int m = 0; m < 8; ++m) {
    int f = t + m * 256;
    int row = f >> 4, cc = f & 15;
    short8 v = *(const short8*)&lo[row * 128 + ((cc ^ ((row & 7) << 1)) * 8)];
    *(short8*)((ushort*)dist + ((size_t)(bm * 128 + row)) * NB + bn * 128 + cc * 8) = v;
  }
}

// ---------------- select: stats threshold -> candidates -> exact refine -> entropy ----
__global__ __launch_bounds__(256) void select_entropy(
    const __half* __restrict__ dist, const float* __restrict__ enc,
    const float* __restrict__ e2, const int* __restrict__ hard,
    const float* __restrict__ maxg, const int* __restrict__ idxs,
    float* __restrict__ out, int s0) {
  __shared__ ushort rowv[NB];      // 16 KB
  __shared__ float qv[NENC];       // 1 KB
  __shared__ float cd[CAP];        // 4 KB
  __shared__ int   cidx[CAP];      // 4 KB
  __shared__ float redf[8];
  __shared__ int   redi[24];
  __shared__ int   chist[NC];
  __shared__ int   ncand, ncnt;
  __shared__ float kthv;

  const int t = threadIdx.x, lane = t & 63, wv = t >> 6;
  const int s = s0 + blockIdx.x;
  const int qi = idxs[s];

  // pass 1: load row + sum/sumsq
  float sum = 0.f, sq = 0.f;
  const short8* src = (const short8*)(dist + (size_t)blockIdx.x * NB);
  #pragma unroll
  for (int u = 0; u < 4; ++u) {
    short8 v = src[t + u * 256];
    ((short8*)rowv)[t + u * 256] = v;
    #pragma unroll
    for (int e = 0; e < 8; ++e) {
      float f = h2f((unsigned short)v[e]);
      sum += f; sq += f * f;
    }
  }
  qv[t] = enc[(size_t)qi * NENC + t];
  if (t == 0) { ncand = 0; ncnt = 0; }
  if (t < NC) chist[t] = 0;
  #pragma unroll
  for (int o = 32; o; o >>= 1) { sum += __shfl_down(sum, o, 64); sq += __shfl_down(sq, o, 64); }
  if (lane == 0) { redf[wv] = sum; redf[4 + wv] = sq; }
  __syncthreads();
  float mean = (redf[0] + redf[1] + redf[2] + redf[3]) * (1.0f / NB);
  float msq  = (redf[4] + redf[5] + redf[6] + redf[7]) * (1.0f / NB);
  float sig = sqrtf(fmaxf(msq - mean * mean, 1e-6f));
  float step = fmaxf(sig * 0.25f, 1.0f);
  float base = mean - 13.0f * step;     // thr_j = base + j*step, j=0..4 ~ mean-(3.25..2.25)sig

  // pass 2: count at 5 thresholds, no atomics
  int c[5] = {0, 0, 0, 0, 0};
  for (int u = 0; u < 32; ++u) {
    float v = h2f(rowv[t + u * 256]);
    #pragma unroll
    for (int j = 0; j < 5; ++j) c[j] += (v <= base + j * step) ? 1 : 0;
  }
  #pragma unroll
  for (int j = 0; j < 5; ++j) {
    int cj = c[j];
    #pragma unroll
    for (int o = 32; o; o >>= 1) cj += __shfl_down(cj, o, 64);
    if (lane == 0) redi[wv * 5 + j] = cj;
  }
  __syncthreads();
  float thr = -1.f;
  #pragma unroll
  for (int j = 0; j < 5; ++j) {
    int tot = redi[j] + redi[5 + j] + redi[10 + j] + redi[15 + j];
    if (thr < 0.f && tot >= SEL) thr = base + j * step;
  }
  // rare fallback ladder (block-uniform loop)
  for (int ext = 1; thr < 0.f && ext <= 10; ++ext) {
    float th2 = base + 4 * step + ext * (2.0f * step);
    int lc = 0;
    for (int u = 0; u < 32; ++u) lc += (h2f(rowv[t + u * 256]) <= th2) ? 1 : 0;
    #pragma unroll
    for (int o = 32; o; o >>= 1) lc += __shfl_down(lc, o, 64);
    __syncthreads();
    if (lane == 0) redi[20 + wv] = lc;
    __syncthreads();
    int tot = redi[20] + redi[21] + redi[22] + redi[23];
    if (tot >= SEL) thr = th2;
  }
  if (thr < 0.f) thr = 1e30f;

  // pass 3: collect candidates (few atomics)
  float cthr = thr + CMARG;
  for (int u = 0; u < 32; ++u) {
    int i = t + u * 256;
    if (h2f(rowv[i]) <= cthr) {
      int p = atomicAdd(&ncand, 1);
      if (p < CAP) cidx[p] = i;
    }
  }
  __syncthreads();
  int nc = ncand < CAP ? ncand : CAP;
  float q2v = e2[qi];

  // pass 4: exact f32 distances, 16-lane groups, 2 candidates/group (32 in flight)
  const int g = lane >> 4, sl = lane & 15;
  float4 qf[4];
  #pragma unroll
  for (int j = 0; j < 4; ++j) qf[j] = ((const float4*)qv)[sl * 4 + j];

  for (int b0 = 0; b0 < nc; b0 += 32) {
    int c0 = b0 + (wv * 4 + g) * 2;
    float p0 = 0.f, p1 = 0.f;
    int i0 = -1, i1 = -1;
    if (c0 < nc) {
      i0 = cidx[c0];
      const float4* er = (const float4*)(enc + (size_t)i0 * NENC);
      #pragma unroll
      for (int j = 0; j < 4; ++j) {
        float4 ev = er[sl * 4 + j];
        p0 += qf[j].x * ev.x + qf[j].y * ev.y + qf[j].z * ev.z + qf[j].w * ev.w;
      }
    }
    if (c0 + 1 < nc) {
      i1 = cidx[c0 + 1];
      const float4* er = (const float4*)(enc + (size_t)i1 * NENC);
      #pragma unroll
      for (int j = 0; j < 4; ++j) {
        float4 ev = er[sl * 4 + j];
        p1 += qf[j].x * ev.x + qf[j].y * ev.y + qf[j].z * ev.z + qf[j].w * ev.w;
      }
    }
    #pragma unroll
    for (int o = 1; o < 16; o <<= 1) {
      p0 += __shfl_xor(p0, o, 64);
      p1 += __shfl_xor(p1, o, 64);
    }
    if (sl == 0 && i0 >= 0) cd[c0]     = sqrtf(fmaxf((q2v - 2.0f * p0) + e2[i0], 0.f));
    if (sl == 0 && i1 >= 0) cd[c0 + 1] = sqrtf(fmaxf((q2v - 2.0f * p1) + e2[i1], 0.f));
  }
  __syncthreads();

  // pass 5: exact 26th smallest among candidates
  for (int c0 = t; c0 < nc; c0 += 256) {
    float mv = cd[c0];
    int less = 0, eq = 0;
    for (int j = 0; j < nc; ++j) { float o = cd[j]; less += (o < mv); eq += (o == mv); }
    if (less <= SEL - 1 && less + eq > SEL - 1) kthv = mv;
  }
  __syncthreads();
  float kv = kthv;

  // pass 6: mask + cluster counts + entropy
  for (int c0 = t; c0 < nc; c0 += 256) {
    if (cd[c0] < kv) {
      atomicAdd(&chist[hard[cidx[c0]]], 1);
      atomicAdd(&ncnt, 1);
    }
  }
  __syncthreads();
  if (t == 0) {
    float fn = (float)ncnt;
    float pur = 0.f;
    for (int cc = 0; cc < NC; ++cc) {
      float p = (float)chist[cc] / fn;
      pur -= p * logf(p + 1e-5f);
    }
    out[s] = pur * maxg[qi];
  }
}

// ---------------- launch ----------------
extern "C" void kernel_launch(void* const* d_in, const int* in_sizes, int n_in,
                              void* d_out, int out_size, void* d_ws, size_t ws_size,
                              hipStream_t stream) {
  const float* enc = (const float*)d_in[0];
  const float* cat = (const float*)d_in[1];
  const int* idxs = (const int*)d_in[2];
  float* out = (float*)d_out;

  char* ws = (char*)d_ws;
  float* e2   = (float*)ws;
  float* maxg = e2 + NB;
  int*   hard = (int*)(maxg + NB);
  float* q2   = (float*)(hard + NB);
  ushort* Abf = (ushort*)(q2 + NB);
  ushort* Bbf = Abf + (size_t)NS * NENC;
  __half* dist = (__half*)(Bbf + (size_t)NB * NENC);

  size_t head = (size_t)((char*)dist - ws);
  size_t avail = ws_size > head ? ws_size - head : 0;
  long long cmax = (long long)(avail / ((size_t)NB * 2));
  int chunk = (int)(cmax > NS ? NS : cmax);
  chunk &= ~127;
  if (chunk < 128) chunk = 128;

  prep_kernel<<<dim3(NB / 4), dim3(256), 0, stream>>>(enc, cat, e2, maxg, hard, Bbf);
  gatherA<<<dim3(NS * NENC / 4 / 256), dim3(256), 0, stream>>>(enc, idxs, e2, Abf, q2);

  for (int s0 = 0; s0 < NS; s0 += chunk) {
    int rows = (NS - s0 < chunk) ? (NS - s0) : chunk;
    d2gemm<<<dim3(rows / 128, NB / 128), dim3(256), 0, stream>>>(
        Abf + (size_t)s0 * NENC, Bbf, q2 + s0, e2, dist);
    select_entropy<<<dim3(rows), dim3(256), 0, stream>>>(
        dist, enc, e2, hard, maxg, idxs, out, s0);
  }
}